// Round 5
// baseline (226.158 us; speedup 1.0000x reference)
//
#include <hip/hip_runtime.h>
#include <stdint.h>

#define N_TOK 32768
#define TD 512
#define GE 160
#define WSTRIDE (GE * GE)          // 25600
#define HSTR 172                   // LDS row stride (ushorts): 0 conflicts measured

typedef __attribute__((ext_vector_type(8))) short short8;   // 8 bf16
typedef __attribute__((ext_vector_type(4))) float f32x4;    // MFMA C/D
typedef __attribute__((ext_vector_type(4))) unsigned short us4;

// ---- ws layout (byte offsets), main path ----
#define OFF_L0C   0                          // 160 * float4 = 2560 B
#define OFF_WF    2816                       // 16B aligned
#define WS_REQ    (OFF_WF + 250 * 3072)      // 770816
// legacy path offsets (exclusive with main path)
#define LOFF_CNT  0
#define LOFF_META 256
#define LOFF_OPV  (LOFF_META + 4 * N_TOK)

__device__ __forceinline__ uint32_t nib_first(uint64_t m, int field) {
    uint32_t bits = (uint32_t)((m >> (field * 16)) & 0xFFFFull);
    return bits ? (uint32_t)__builtin_ctz(bits) : 0u;
}
__device__ __forceinline__ unsigned short bf16_rne(float f) {
    uint32_t u = __builtin_bit_cast(uint32_t, f);
    return (unsigned short)((u + 0x7FFFu + ((u >> 16) & 1u)) >> 16);
}
__device__ __forceinline__ float bf16_f(unsigned short h) {
    uint32_t u = ((uint32_t)h) << 16;
    return __builtin_bit_cast(float, u);
}
__device__ __forceinline__ void split3(float v, unsigned short& s1,
                                       unsigned short& s2, unsigned short& s3) {
    s1 = bf16_rne(v); float r  = v - bf16_f(s1);
    s2 = bf16_rne(r); float r2 = r - bf16_f(s2);
    s3 = bf16_rne(r2);
}

// ===== kernel A: frag-ordered bf16x3 W planes + L0 coeff pack (64 blocks) =====
__global__ __launch_bounds__(256) void wprep_kernel(
        const float* __restrict__ W, const float* __restrict__ b,
        float4* __restrict__ l0c, unsigned short* __restrict__ Wf) {
    int wid = (int)blockIdx.x * 256 + (int)threadIdx.x;
    if (wid < 16000) {
        int tile = wid >> 6, lane = wid & 63;
        int l = 1 + tile / 50, rem = tile % 50, kt = rem / 10, mt = rem % 10;
        int li = lane & 15, q = lane >> 4;
        const float* src = W + (size_t)l * WSTRIDE + (size_t)(16 * mt + li) * GE +
                           32 * kt + 8 * q;
        short8 A1, A2, A3;
        #pragma unroll
        for (int j = 0; j < 8; ++j) {
            unsigned short s1, s2, s3;
            split3(src[j], s1, s2, s3);
            A1[j] = (short)s1; A2[j] = (short)s2; A3[j] = (short)s3;
        }
        unsigned short* tb = Wf + (size_t)tile * 1536 + lane * 8;
        *(short8*)(tb)        = A1;
        *(short8*)(tb + 512)  = A2;
        *(short8*)(tb + 1024) = A3;
    } else if (wid < 16160) {
        int n = wid - 16000;
        l0c[n] = make_float4(W[(size_t)n * GE + 0], W[(size_t)n * GE + 1],
                             W[(size_t)n * GE + 30], b[n]);
    }
}

// ===== mega kernel: copy + decode + MFMA MLP + one-hot write, all in-block ====
// 2048 blocks x 256 threads; block owns 16 consecutive tokens (32 positions).
__global__ __launch_bounds__(256, 4) void mega_kernel(
        const float* __restrict__ x, const float* __restrict__ W,
        const float* __restrict__ b, float* __restrict__ out,
        const float4* __restrict__ l0c, const unsigned short* __restrict__ Wf) {
    __shared__ unsigned short hs[3][32][HSTR];   // 33 KB
    __shared__ uint32_t nibs[16];
    __shared__ float    opx[16];
    __shared__ uint32_t actarr[16];

    const int tid  = (int)threadIdx.x;
    const int lane = tid & 63;
    const int wv   = __builtin_amdgcn_readfirstlane(tid >> 6);   // 0..3
    const int q    = lane >> 4;
    const int li   = lane & 15;
    const int half = lane >> 5, posid = lane & 31;
    const int t0   = (int)blockIdx.x * 16;

    // ---- 1. copy loads (prefetch; 16 tokens = 2048 float4, 8/thread) ----
    float4 cp[8];
    const float4* s4 = (const float4*)x + (size_t)blockIdx.x * 2048;
    #pragma unroll
    for (int i = 0; i < 8; ++i) cp[i] = s4[tid + 256 * i];

    // ---- 2. in-block decode: wave wv handles tokens 4*wv .. 4*wv+3 ----
    #pragma unroll
    for (int it = 0; it < 4; ++it) {
        int tl = wv * 4 + it;
        size_t base = (size_t)(t0 + tl) * TD;
        float nv = x[base + 64 + lane];
        uint64_t m = __ballot(nv > 0.5f);
        if (lane == 0) {
            float g0 = x[base], g1 = x[base + 1];
            actarr[tl] = (g0 >= 0.5f && g1 >= 0.5f) ? 1u : 0u;
            nibs[tl] = nib_first(m, 0) | (nib_first(m, 1) << 4) |
                       (nib_first(m, 2) << 8) | (nib_first(m, 3) << 12);
            opx[tl] = x[base + 29];               // OPCODE_BASE + 27
        }
    }
    __syncthreads();

    // ---- 3. gated copy stores: skip [128,160) region for active tokens ----
    {
        float4* d4 = (float4*)out + (size_t)blockIdx.x * 2048;
        #pragma unroll
        for (int i = 0; i < 8; ++i) {
            int f4 = tid + 256 * i;
            int tl = f4 >> 7, w = f4 & 127;
            bool skip = (w >= 32) && (w < 40) && (actarr[tl] != 0u);
            if (!skip) d4[f4] = cp[i];
        }
    }

    // ---- 4. layer 0 (exact fp32): all 32 positions, inactive get zeros ----
    {
        int tl = posid >> 1, p = posid & 1;
        uint32_t nib = nibs[tl];
        float na  = (float)((nib >> (4 * p)) & 0xFu);
        float nb_ = (float)((nib >> (8 + 4 * p)) & 0xFu);
        float op  = opx[tl];
        #pragma unroll
        for (int g = 0; g < 5; ++g) {
            int nb4 = 40 * wv + 20 * half + 4 * g;
            us4 p1, p2, p3;
            #pragma unroll
            for (int r = 0; r < 4; ++r) {
                float4 cc = l0c[nb4 + r];
                float c = cc.w;
                c = fmaf(cc.x, na, c);
                c = fmaf(cc.y, nb_, c);
                c = fmaf(cc.z, op, c);
                c = fmaxf(c, 0.f);
                unsigned short s1, s2, s3;
                split3(c, s1, s2, s3);
                p1[r] = s1; p2[r] = s2; p3[r] = s3;
            }
            *(us4*)&hs[0][posid][nb4] = p1;
            *(us4*)&hs[1][posid][nb4] = p2;
            *(us4*)&hs[2][posid][nb4] = p3;
        }
    }
    __syncthreads();

    // ---- 5. layers 1..5: bf16x3 MFMA (identical math to R3/R4, absmax 0) ----
    const int mstart_tab[4] = {0, 3, 5, 7};
    const int mcnt_tab[4]   = {3, 2, 2, 3};
    const int mystart = mstart_tab[wv], mycnt = mcnt_tab[wv];

    for (int l = 1; l < 6; ++l) {
        const float* bl = b + l * GE;
        f32x4 acc[3][2];
        #pragma unroll
        for (int mi = 0; mi < 3; ++mi)
            #pragma unroll
            for (int nt = 0; nt < 2; ++nt)
                acc[mi][nt] = (f32x4){0.f, 0.f, 0.f, 0.f};

        for (int kt = 0; kt < 5; ++kt) {
            const int k0 = 32 * kt + 8 * q;
            short8 B1[2], B2[2], B3[2];
            #pragma unroll
            for (int nt = 0; nt < 2; ++nt) {
                int pos = 16 * nt + li;
                us4 lo1 = *(const us4*)&hs[0][pos][k0];
                us4 hi1 = *(const us4*)&hs[0][pos][k0 + 4];
                us4 lo2 = *(const us4*)&hs[1][pos][k0];
                us4 hi2 = *(const us4*)&hs[1][pos][k0 + 4];
                us4 lo3 = *(const us4*)&hs[2][pos][k0];
                us4 hi3 = *(const us4*)&hs[2][pos][k0 + 4];
                #pragma unroll
                for (int j = 0; j < 4; ++j) {
                    B1[nt][j] = (short)lo1[j]; B1[nt][4 + j] = (short)hi1[j];
                    B2[nt][j] = (short)lo2[j]; B2[nt][4 + j] = (short)hi2[j];
                    B3[nt][j] = (short)lo3[j]; B3[nt][4 + j] = (short)hi3[j];
                }
            }
            #pragma unroll
            for (int mi = 0; mi < 3; ++mi) {
                if (mi < mycnt) {
                    int mt = mystart + mi;
                    int tidx = ((l - 1) * 5 + kt) * 10 + mt;
                    const unsigned short* tb = Wf + (size_t)tidx * 1536 + lane * 8;
                    short8 A1 = *(const short8*)(tb);
                    short8 A2 = *(const short8*)(tb + 512);
                    short8 A3 = *(const short8*)(tb + 1024);
                    #pragma unroll
                    for (int nt = 0; nt < 2; ++nt) {
                        f32x4 a = acc[mi][nt];
                        a = __builtin_amdgcn_mfma_f32_16x16x32_bf16(A1, B1[nt], a, 0, 0, 0);
                        a = __builtin_amdgcn_mfma_f32_16x16x32_bf16(A1, B2[nt], a, 0, 0, 0);
                        a = __builtin_amdgcn_mfma_f32_16x16x32_bf16(A2, B1[nt], a, 0, 0, 0);
                        a = __builtin_amdgcn_mfma_f32_16x16x32_bf16(A2, B2[nt], a, 0, 0, 0);
                        a = __builtin_amdgcn_mfma_f32_16x16x32_bf16(A1, B3[nt], a, 0, 0, 0);
                        a = __builtin_amdgcn_mfma_f32_16x16x32_bf16(A3, B1[nt], a, 0, 0, 0);
                        acc[mi][nt] = a;
                    }
                }
            }
        }
        __syncthreads();   // all reads of layer l-1 done before overwrite
        #pragma unroll
        for (int mi = 0; mi < 3; ++mi) {
            if (mi < mycnt) {
                int nb4 = 16 * (mystart + mi) + 4 * q;
                #pragma unroll
                for (int nt = 0; nt < 2; ++nt) {
                    int pos = 16 * nt + li;
                    us4 p1, p2, p3;
                    #pragma unroll
                    for (int r = 0; r < 4; ++r) {
                        float v = fmaxf(acc[mi][nt][r] + bl[nb4 + r], 0.f);
                        unsigned short s1, s2, s3;
                        split3(v, s1, s2, s3);
                        p1[r] = s1; p2[r] = s2; p3[r] = s3;
                    }
                    *(us4*)&hs[0][pos][nb4] = p1;
                    *(us4*)&hs[1][pos][nb4] = p2;
                    *(us4*)&hs[2][pos][nb4] = p3;
                }
            }
        }
        __syncthreads();
    }

    // ---- 6. layer 6 (row RESULT=2 only) + direct [128,160) region write ----
    if (wv == 0) {
        const float* W6 = W + 6 * WSTRIDE + 2 * GE;
        float accp = (half == 0) ? b[6 * GE + 2] : 0.f;
        #pragma unroll
        for (int kb = 0; kb < 10; ++kb) {
            int k0 = 80 * half + 8 * kb;
            us4 a0 = *(const us4*)&hs[0][posid][k0];
            us4 a1 = *(const us4*)&hs[0][posid][k0 + 4];
            us4 b0 = *(const us4*)&hs[1][posid][k0];
            us4 b1 = *(const us4*)&hs[1][posid][k0 + 4];
            us4 c0 = *(const us4*)&hs[2][posid][k0];
            us4 c1 = *(const us4*)&hs[2][posid][k0 + 4];
            const float4* w6f = (const float4*)(W6 + k0);
            float4 w0 = w6f[0], w1 = w6f[1];
            const float* wp0 = (const float*)&w0;
            const float* wp1 = (const float*)&w1;
            #pragma unroll
            for (int j = 0; j < 4; ++j) {
                float v = (bf16_f(a0[j]) + bf16_f(b0[j])) + bf16_f(c0[j]);
                accp = fmaf(v, wp0[j], accp);
            }
            #pragma unroll
            for (int j = 0; j < 4; ++j) {
                float v = (bf16_f(a1[j]) + bf16_f(b1[j])) + bf16_f(c1[j]);
                accp = fmaf(v, wp1[j], accp);
            }
        }
        float full = accp + __shfl_down(accp, 32);
        int res = (int)fminf(fmaxf(rintf(full), 0.f), 15.f);
        int rhi = __shfl_down(res, 1);
        if (lane < 32 && !(lane & 1)) {
            int tl = lane >> 1;
            if (actarr[tl] != 0u) {
                int tok = t0 + tl;
                const float4* xf = (const float4*)(x + (size_t)tok * TD + 128);
                float4* of = (float4*)(out + (size_t)tok * TD + 128);
                int rl = res, rh = 16 + rhi;
                #pragma unroll
                for (int i = 0; i < 8; ++i) {
                    float4 v = xf[i];
                    int e = 4 * i;
                    v.x += ((e == rl) || (e == rh)) ? 2.f : 0.f;
                    v.y += ((e + 1 == rl) || (e + 1 == rh)) ? 2.f : 0.f;
                    v.z += ((e + 2 == rl) || (e + 2 == rh)) ? 2.f : 0.f;
                    v.w += ((e + 3 == rl) || (e + 3 == rh)) ? 2.f : 0.f;
                    of[i] = v;
                }
            }
        }
    }
}

// ============ legacy fallback (R2 path, exact fp32) ============
__global__ __launch_bounds__(256) void prep_legacy(
        const float* __restrict__ x, float* __restrict__ out,
        uint32_t* __restrict__ cnt, uint32_t* __restrict__ meta,
        float* __restrict__ opv, int do_compact) {
    __shared__ uint32_t l_meta[64];
    __shared__ float    l_opv[64];
    __shared__ uint32_t l_cnt, l_base;
    const int tid = (int)threadIdx.x;
    if (tid == 0) l_cnt = 0;
    size_t blk = (size_t)blockIdx.x * 4096;
    const float4* s4 = ((const float4*)x) + blk;
    float4*       d4 = ((float4*)out) + blk;
    #pragma unroll
    for (int i = 0; i < 16; ++i) d4[tid + 256 * i] = s4[tid + 256 * i];
    if (!do_compact) return;
    __syncthreads();
    const int lane = tid & 63, w = tid >> 6;
    for (int it = 0; it < 8; ++it) {
        int tok = (int)blockIdx.x * 32 + it * 4 + w;
        size_t base = (size_t)tok * TD;
        float nv = x[base + 64 + lane];
        uint64_t m = __ballot(nv > 0.5f);
        if (lane == 0) {
            float g0 = x[base], g1 = x[base + 1];
            if (g0 >= 0.5f && g1 >= 0.5f) {
                uint32_t idx = atomicAdd(&l_cnt, 1u);
                l_meta[idx] = (uint32_t)tok | (nib_first(m, 0) << 15) |
                              (nib_first(m, 1) << 19) | (nib_first(m, 2) << 23) |
                              (nib_first(m, 3) << 27);
                l_opv[idx] = x[base + 29];
            }
        }
    }
    __syncthreads();
    if (tid == 0) l_base = atomicAdd(cnt, l_cnt);
    __syncthreads();
    if ((uint32_t)tid < l_cnt) {
        meta[l_base + tid] = l_meta[tid];
        opv[l_base + tid]  = l_opv[tid];
    }
}

template <bool COMPACT>
__global__ __launch_bounds__(1024) void mlp_legacy(
        const float* __restrict__ x, const float* __restrict__ W,
        const float* __restrict__ b, float* __restrict__ out,
        const uint32_t* __restrict__ cnt, const uint32_t* __restrict__ meta,
        const float* __restrict__ opv) {
    __shared__ float h[GE][64];
    const int lane = (int)(threadIdx.x & 63u);
    const int w    = __builtin_amdgcn_readfirstlane((int)(threadIdx.x >> 6));
    const int p    = lane & 1;
    const uint32_t count   = COMPACT ? *cnt : (uint32_t)N_TOK;
    const uint32_t nchunks = (count + 31u) >> 5;
    for (uint32_t ch = blockIdx.x; ch < nchunks; ch += gridDim.x) {
        uint32_t slot = ch * 32u + (uint32_t)(lane >> 1);
        bool active = slot < count;
        int tok = 0;
        float na = 0.f, nb = 0.f, op = 0.f;
        if (COMPACT) {
            if (active) {
                uint32_t mt = meta[slot];
                tok = (int)(mt & 0x7FFFu);
                uint32_t nib = mt >> 15;
                na = (float)((nib >> (p * 4)) & 0xFu);
                nb = (float)((nib >> (8 + p * 4)) & 0xFu);
                op = opv[slot];
            }
        } else {
            tok = (int)slot;
            if (active) {
                size_t tb = (size_t)tok * TD;
                float g0 = x[tb], g1 = x[tb + 1];
                active = (g0 >= 0.5f) && (g1 >= 0.5f);
                if (active) {
                    const float* ap = x + tb + 64 + 16 * p;
                    const float* bp = x + tb + 96 + 16 * p;
                    #pragma unroll
                    for (int i = 15; i >= 0; --i) { if (ap[i] > 0.5f) na = (float)i; }
                    #pragma unroll
                    for (int i = 15; i >= 0; --i) { if (bp[i] > 0.5f) nb = (float)i; }
                    op = x[tb + 29];
                }
            }
        }
        float c[10];
        {
            #pragma unroll
            for (int j = 0; j < 10; ++j) {
                int n = 10 * w + j;
                float cc = b[n];
                cc = fmaf(W[n * GE + 0],  na, cc);
                cc = fmaf(W[n * GE + 1],  nb, cc);
                cc = fmaf(W[n * GE + 30], op, cc);
                c[j] = fmaxf(cc, 0.f);
            }
        }
        __syncthreads();
        #pragma unroll
        for (int j = 0; j < 10; ++j) h[10 * w + j][lane] = c[j];
        __syncthreads();
        for (int l = 1; l < 6; ++l) {
            const float* Wl = W + l * WSTRIDE;
            const float* bl = b + l * GE;
            #pragma unroll
            for (int j = 0; j < 10; ++j) c[j] = bl[10 * w + j];
            for (int k0 = 0; k0 < GE; k0 += 16) {
                float hr[16];
                #pragma unroll
                for (int kk = 0; kk < 16; ++kk) hr[kk] = h[k0 + kk][lane];
                #pragma unroll
                for (int j = 0; j < 10; ++j) {
                    const float* wr = Wl + (10 * w + j) * GE + k0;
                    #pragma unroll
                    for (int kk = 0; kk < 16; ++kk)
                        c[j] = fmaf(hr[kk], wr[kk], c[j]);
                }
            }
            __syncthreads();
            #pragma unroll
            for (int j = 0; j < 10; ++j)
                h[10 * w + j][lane] = fmaxf(c[j], 0.f);
            __syncthreads();
        }
        if (w == 0) {
            const float* W6 = W + 6 * WSTRIDE + 2 * GE;
            float acc = b[6 * GE + 2];
            #pragma unroll 16
            for (int k = 0; k < GE; ++k) acc = fmaf(h[k][lane], W6[k], acc);
            if (active) {
                float r = rintf(acc);
                r = fminf(fmaxf(r, 0.f), 15.f);
                int res = (int)r;
                out[(size_t)tok * TD + 128 + 16 * p + res] += 2.0f;
            }
        }
    }
}

extern "C" void kernel_launch(void* const* d_in, const int* in_sizes, int n_in,
                              void* d_out, int out_size, void* d_ws, size_t ws_size,
                              hipStream_t stream) {
    const float* x = (const float*)d_in[0];
    const float* W = (const float*)d_in[1];
    const float* b = (const float*)d_in[2];
    float* out = (float*)d_out;

    if (ws_size >= (size_t)WS_REQ) {
        float4* l0c = (float4*)((char*)d_ws + OFF_L0C);
        unsigned short* Wf = (unsigned short*)((char*)d_ws + OFF_WF);
        wprep_kernel<<<64, 256, 0, stream>>>(W, b, l0c, Wf);
        mega_kernel<<<N_TOK / 16, 256, 0, stream>>>(x, W, b, out, l0c, Wf);
    } else {
        uint32_t* cnt  = (uint32_t*)((char*)d_ws + LOFF_CNT);
        uint32_t* meta = (uint32_t*)((char*)d_ws + LOFF_META);
        float*    opv  = (float*)((char*)d_ws + LOFF_OPV);
        bool compact = ws_size >= (size_t)(256 + 8 * (size_t)N_TOK);
        if (compact) hipMemsetAsync(d_ws, 0, 4, stream);
        prep_legacy<<<N_TOK / 32, 256, 0, stream>>>(x, out, cnt, meta, opv,
                                                    compact ? 1 : 0);
        if (compact)
            mlp_legacy<true><<<512, 1024, 0, stream>>>(x, W, b, out, cnt, meta, opv);
        else
            mlp_legacy<false><<<512, 1024, 0, stream>>>(x, W, b, out, cnt, meta, opv);
    }
}

// Round 6
// 185.930 us; speedup vs baseline: 1.2164x; 1.2164x over previous
//
#include <hip/hip_runtime.h>
#include <stdint.h>

#define N_TOK 32768
#define TD 512
#define GE 160
#define WSTRIDE (GE * GE)          // 25600
#define HSTR 172                   // LDS row stride (ushorts): 0 conflicts measured

typedef __attribute__((ext_vector_type(8))) short short8;   // 8 bf16
typedef __attribute__((ext_vector_type(4))) float f32x4;    // MFMA C/D
typedef __attribute__((ext_vector_type(4))) unsigned short us4;

// ---- ws layout (byte offsets), main path ----
#define OFF_L0C   0                          // 160 * float4 = 2560 B
#define OFF_WF    2816                       // 16B aligned
#define WS_REQ    (OFF_WF + 250 * 3072)      // 770816
// legacy path offsets (exclusive with main path)
#define LOFF_CNT  0
#define LOFF_META 256
#define LOFF_OPV  (LOFF_META + 4 * N_TOK)

__device__ __forceinline__ uint32_t nib_first(uint64_t m, int field) {
    uint32_t bits = (uint32_t)((m >> (field * 16)) & 0xFFFFull);
    return bits ? (uint32_t)__builtin_ctz(bits) : 0u;
}
__device__ __forceinline__ unsigned short bf16_rne(float f) {
    uint32_t u = __builtin_bit_cast(uint32_t, f);
    return (unsigned short)((u + 0x7FFFu + ((u >> 16) & 1u)) >> 16);
}
__device__ __forceinline__ float bf16_f(unsigned short h) {
    uint32_t u = ((uint32_t)h) << 16;
    return __builtin_bit_cast(float, u);
}
__device__ __forceinline__ void split3(float v, unsigned short& s1,
                                       unsigned short& s2, unsigned short& s3) {
    s1 = bf16_rne(v); float r  = v - bf16_f(s1);
    s2 = bf16_rne(r); float r2 = r - bf16_f(s2);
    s3 = bf16_rne(r2);
}

// ===== kernel A: frag-ordered bf16x3 W planes + L0 coeff pack (64 blocks) =====
__global__ __launch_bounds__(256) void wprep_kernel(
        const float* __restrict__ W, const float* __restrict__ b,
        float4* __restrict__ l0c, unsigned short* __restrict__ Wf) {
    int wid = (int)blockIdx.x * 256 + (int)threadIdx.x;
    if (wid < 16000) {
        int tile = wid >> 6, lane = wid & 63;
        int l = 1 + tile / 50, rem = tile % 50, kt = rem / 10, mt = rem % 10;
        int li = lane & 15, q = lane >> 4;
        const float* src = W + (size_t)l * WSTRIDE + (size_t)(16 * mt + li) * GE +
                           32 * kt + 8 * q;
        short8 A1, A2, A3;
        #pragma unroll
        for (int j = 0; j < 8; ++j) {
            unsigned short s1, s2, s3;
            split3(src[j], s1, s2, s3);
            A1[j] = (short)s1; A2[j] = (short)s2; A3[j] = (short)s3;
        }
        unsigned short* tb = Wf + (size_t)tile * 1536 + lane * 8;
        *(short8*)(tb)        = A1;
        *(short8*)(tb + 512)  = A2;
        *(short8*)(tb + 1024) = A3;
    } else if (wid < 16160) {
        int n = wid - 16000;
        l0c[n] = make_float4(W[(size_t)n * GE + 0], W[(size_t)n * GE + 1],
                             W[(size_t)n * GE + 30], b[n]);
    }
}

// ===== mega2: copy + decode + IN-BLOCK COMPACTION + MFMA MLP + one-hot =====
// 1024 blocks x 256 threads; block owns 32 tokens. Active positions are packed
// so the MFMA tile count T is ceil(2*act/16) (usually 1-2) instead of fixed 4.
__global__ __launch_bounds__(256, 4) void mega2_kernel(
        const float* __restrict__ x, const float* __restrict__ W,
        const float* __restrict__ b, float* __restrict__ out,
        const float4* __restrict__ l0c, const unsigned short* __restrict__ Wf) {
    __shared__ unsigned short hs[3][32][HSTR];   // 33 KB
    __shared__ uint32_t nibs[32];
    __shared__ float    opx[32];
    __shared__ uint32_t actf[32];
    __shared__ unsigned char list[32];
    __shared__ uint32_t npos_s;

    const int tid  = (int)threadIdx.x;
    const int lane = tid & 63;
    const int wv   = __builtin_amdgcn_readfirstlane(tid >> 6);   // 0..3
    const int q    = lane >> 4;
    const int li   = lane & 15;
    const int half = lane >> 5, posid = lane & 31;
    const int t0   = (int)blockIdx.x * 32;

    // ---- 1. copy everything: 32 tokens = 4096 float4, 2 rounds of 8/thread ----
    {
        const float4* s4 = (const float4*)x + (size_t)blockIdx.x * 4096;
        float4* d4 = (float4*)out + (size_t)blockIdx.x * 4096;
        #pragma unroll
        for (int rnd = 0; rnd < 2; ++rnd) {
            float4 t[8];
            #pragma unroll
            for (int i = 0; i < 8; ++i) t[i] = s4[tid + 256 * (8 * rnd + i)];
            #pragma unroll
            for (int i = 0; i < 8; ++i) d4[tid + 256 * (8 * rnd + i)] = t[i];
        }
    }

    // ---- 2. decode: wave wv handles tokens 8wv..8wv+7 (L1/L2-hot reads) ----
    #pragma unroll
    for (int it = 0; it < 8; ++it) {
        int tl = wv * 8 + it;
        size_t base = (size_t)(t0 + tl) * TD;
        float nv = x[base + 64 + lane];
        uint64_t m = __ballot(nv > 0.5f);
        if (lane == 0) {
            float g0 = x[base], g1 = x[base + 1];
            actf[tl] = (g0 >= 0.5f && g1 >= 0.5f) ? 1u : 0u;
            nibs[tl] = nib_first(m, 0) | (nib_first(m, 1) << 4) |
                       (nib_first(m, 2) << 8) | (nib_first(m, 3) << 12);
            opx[tl] = x[base + 29];               // OPCODE_BASE + 27
        }
    }
    __syncthreads();

    // ---- 3. in-block compaction (wave 0) ----
    if (tid < 64) {
        bool a = (lane < 32) ? (actf[lane] != 0u) : false;
        uint64_t mask = __ballot(a);
        if (a) {
            int j = __popcll(mask & ((1ull << lane) - 1ull));
            list[j] = (unsigned char)lane;
        }
        if (lane == 0) npos_s = 2u * (uint32_t)__popcll(mask);
    }
    __syncthreads();
    const int npos = (int)npos_s;   // block-uniform, even

    const int mstart_tab[4] = {0, 3, 5, 7};
    const int mcnt_tab[4]   = {3, 2, 2, 3};
    const int mystart = mstart_tab[wv], mycnt = mcnt_tab[wv];

    for (int pb = 0; pb < npos; pb += 32) {
        const int T = min(2, (npos - pb + 15) >> 4);   // n-tiles this pass

        // ---- 4. layer 0 (exact fp32) on packed positions ----
        {
            int pp = pb + posid;
            float na = 0.f, nb_ = 0.f, op = 0.f;
            if (pp < npos) {
                int tl = (int)list[pp >> 1];
                int p = pp & 1;
                uint32_t nib = nibs[tl];
                na  = (float)((nib >> (4 * p)) & 0xFu);
                nb_ = (float)((nib >> (8 + 4 * p)) & 0xFu);
                op  = opx[tl];
            }
            #pragma unroll
            for (int g = 0; g < 5; ++g) {
                int nb4 = 40 * wv + 20 * half + 4 * g;
                us4 p1, p2, p3;
                #pragma unroll
                for (int r = 0; r < 4; ++r) {
                    float4 cc = l0c[nb4 + r];
                    float c = cc.w;
                    c = fmaf(cc.x, na, c);
                    c = fmaf(cc.y, nb_, c);
                    c = fmaf(cc.z, op, c);
                    c = fmaxf(c, 0.f);
                    unsigned short s1, s2, s3;
                    split3(c, s1, s2, s3);
                    p1[r] = s1; p2[r] = s2; p3[r] = s3;
                }
                *(us4*)&hs[0][posid][nb4] = p1;
                *(us4*)&hs[1][posid][nb4] = p2;
                *(us4*)&hs[2][posid][nb4] = p3;
            }
        }
        __syncthreads();

        // ---- 5. layers 1..5: bf16x3 MFMA on T n-tiles ----
        for (int l = 1; l < 6; ++l) {
            const float* bl = b + l * GE;
            f32x4 acc[3][2];
            #pragma unroll
            for (int mi = 0; mi < 3; ++mi)
                #pragma unroll
                for (int nt = 0; nt < 2; ++nt)
                    acc[mi][nt] = (f32x4){0.f, 0.f, 0.f, 0.f};

            for (int kt = 0; kt < 5; ++kt) {
                const int k0 = 32 * kt + 8 * q;
                short8 B1[2], B2[2], B3[2];
                #pragma unroll
                for (int nt = 0; nt < 2; ++nt) {
                    if (nt < T) {
                        int pos = 16 * nt + li;
                        us4 lo1 = *(const us4*)&hs[0][pos][k0];
                        us4 hi1 = *(const us4*)&hs[0][pos][k0 + 4];
                        us4 lo2 = *(const us4*)&hs[1][pos][k0];
                        us4 hi2 = *(const us4*)&hs[1][pos][k0 + 4];
                        us4 lo3 = *(const us4*)&hs[2][pos][k0];
                        us4 hi3 = *(const us4*)&hs[2][pos][k0 + 4];
                        #pragma unroll
                        for (int j = 0; j < 4; ++j) {
                            B1[nt][j] = (short)lo1[j]; B1[nt][4 + j] = (short)hi1[j];
                            B2[nt][j] = (short)lo2[j]; B2[nt][4 + j] = (short)hi2[j];
                            B3[nt][j] = (short)lo3[j]; B3[nt][4 + j] = (short)hi3[j];
                        }
                    }
                }
                #pragma unroll
                for (int mi = 0; mi < 3; ++mi) {
                    if (mi < mycnt) {
                        int mt = mystart + mi;
                        int tidx = ((l - 1) * 5 + kt) * 10 + mt;
                        const unsigned short* tb = Wf + (size_t)tidx * 1536 + lane * 8;
                        short8 A1 = *(const short8*)(tb);
                        short8 A2 = *(const short8*)(tb + 512);
                        short8 A3 = *(const short8*)(tb + 1024);
                        #pragma unroll
                        for (int nt = 0; nt < 2; ++nt) {
                            if (nt < T) {
                                f32x4 a = acc[mi][nt];
                                a = __builtin_amdgcn_mfma_f32_16x16x32_bf16(A1, B1[nt], a, 0, 0, 0);
                                a = __builtin_amdgcn_mfma_f32_16x16x32_bf16(A1, B2[nt], a, 0, 0, 0);
                                a = __builtin_amdgcn_mfma_f32_16x16x32_bf16(A2, B1[nt], a, 0, 0, 0);
                                a = __builtin_amdgcn_mfma_f32_16x16x32_bf16(A2, B2[nt], a, 0, 0, 0);
                                a = __builtin_amdgcn_mfma_f32_16x16x32_bf16(A1, B3[nt], a, 0, 0, 0);
                                a = __builtin_amdgcn_mfma_f32_16x16x32_bf16(A3, B1[nt], a, 0, 0, 0);
                                acc[mi][nt] = a;
                            }
                        }
                    }
                }
            }
            __syncthreads();   // all reads of layer l-1 done before overwrite
            #pragma unroll
            for (int mi = 0; mi < 3; ++mi) {
                if (mi < mycnt) {
                    int nb4 = 16 * (mystart + mi) + 4 * q;
                    #pragma unroll
                    for (int nt = 0; nt < 2; ++nt) {
                        if (nt < T) {
                            int pos = 16 * nt + li;
                            us4 p1, p2, p3;
                            #pragma unroll
                            for (int r = 0; r < 4; ++r) {
                                float v = fmaxf(acc[mi][nt][r] + bl[nb4 + r], 0.f);
                                unsigned short s1, s2, s3;
                                split3(v, s1, s2, s3);
                                p1[r] = s1; p2[r] = s2; p3[r] = s3;
                            }
                            *(us4*)&hs[0][pos][nb4] = p1;
                            *(us4*)&hs[1][pos][nb4] = p2;
                            *(us4*)&hs[2][pos][nb4] = p3;
                        }
                    }
                }
            }
            __syncthreads();
        }

        // ---- 6. layer 6 (row RESULT=2) + one-hot overwrite (x + 2.0) ----
        if (wv == 0) {
            const float* W6 = W + 6 * WSTRIDE + 2 * GE;
            float accp = (half == 0) ? b[6 * GE + 2] : 0.f;
            #pragma unroll
            for (int kb = 0; kb < 10; ++kb) {
                int k0 = 80 * half + 8 * kb;
                us4 a0 = *(const us4*)&hs[0][posid][k0];
                us4 a1 = *(const us4*)&hs[0][posid][k0 + 4];
                us4 b0 = *(const us4*)&hs[1][posid][k0];
                us4 b1 = *(const us4*)&hs[1][posid][k0 + 4];
                us4 c0 = *(const us4*)&hs[2][posid][k0];
                us4 c1 = *(const us4*)&hs[2][posid][k0 + 4];
                const float4* w6f = (const float4*)(W6 + k0);
                float4 w0 = w6f[0], w1 = w6f[1];
                const float* wp0 = (const float*)&w0;
                const float* wp1 = (const float*)&w1;
                #pragma unroll
                for (int j = 0; j < 4; ++j) {
                    float v = (bf16_f(a0[j]) + bf16_f(b0[j])) + bf16_f(c0[j]);
                    accp = fmaf(v, wp0[j], accp);
                }
                #pragma unroll
                for (int j = 0; j < 4; ++j) {
                    float v = (bf16_f(a1[j]) + bf16_f(b1[j])) + bf16_f(c1[j]);
                    accp = fmaf(v, wp1[j], accp);
                }
            }
            float full = accp + __shfl_down(accp, 32);
            int res = (int)fminf(fmaxf(rintf(full), 0.f), 15.f);
            int rhi = __shfl_down(res, 1);
            if (lane < 32 && !(lane & 1)) {
                int pp = pb + lane;
                if (pp < npos) {       // npos even -> pp+1 valid too
                    int tok = t0 + (int)list[pp >> 1];
                    size_t tb_ = (size_t)tok * TD;
                    // copy store to these addrs completed (barrier vmcnt drain)
                    out[tb_ + 128 + res] = x[tb_ + 128 + res] + 2.0f;
                    out[tb_ + 144 + rhi] = x[tb_ + 144 + rhi] + 2.0f;
                }
            }
        }
        __syncthreads();   // protect hs before next pass's layer-0 writes
    }
}

// ============ legacy fallback (R2 path, exact fp32) ============
__global__ __launch_bounds__(256) void prep_legacy(
        const float* __restrict__ x, float* __restrict__ out,
        uint32_t* __restrict__ cnt, uint32_t* __restrict__ meta,
        float* __restrict__ opv, int do_compact) {
    __shared__ uint32_t l_meta[64];
    __shared__ float    l_opv[64];
    __shared__ uint32_t l_cnt, l_base;
    const int tid = (int)threadIdx.x;
    if (tid == 0) l_cnt = 0;
    size_t blk = (size_t)blockIdx.x * 4096;
    const float4* s4 = ((const float4*)x) + blk;
    float4*       d4 = ((float4*)out) + blk;
    #pragma unroll
    for (int i = 0; i < 16; ++i) d4[tid + 256 * i] = s4[tid + 256 * i];
    if (!do_compact) return;
    __syncthreads();
    const int lane = tid & 63, w = tid >> 6;
    for (int it = 0; it < 8; ++it) {
        int tok = (int)blockIdx.x * 32 + it * 4 + w;
        size_t base = (size_t)tok * TD;
        float nv = x[base + 64 + lane];
        uint64_t m = __ballot(nv > 0.5f);
        if (lane == 0) {
            float g0 = x[base], g1 = x[base + 1];
            if (g0 >= 0.5f && g1 >= 0.5f) {
                uint32_t idx = atomicAdd(&l_cnt, 1u);
                l_meta[idx] = (uint32_t)tok | (nib_first(m, 0) << 15) |
                              (nib_first(m, 1) << 19) | (nib_first(m, 2) << 23) |
                              (nib_first(m, 3) << 27);
                l_opv[idx] = x[base + 29];
            }
        }
    }
    __syncthreads();
    if (tid == 0) l_base = atomicAdd(cnt, l_cnt);
    __syncthreads();
    if ((uint32_t)tid < l_cnt) {
        meta[l_base + tid] = l_meta[tid];
        opv[l_base + tid]  = l_opv[tid];
    }
}

template <bool COMPACT>
__global__ __launch_bounds__(1024) void mlp_legacy(
        const float* __restrict__ x, const float* __restrict__ W,
        const float* __restrict__ b, float* __restrict__ out,
        const uint32_t* __restrict__ cnt, const uint32_t* __restrict__ meta,
        const float* __restrict__ opv) {
    __shared__ float h[GE][64];
    const int lane = (int)(threadIdx.x & 63u);
    const int w    = __builtin_amdgcn_readfirstlane((int)(threadIdx.x >> 6));
    const int p    = lane & 1;
    const uint32_t count   = COMPACT ? *cnt : (uint32_t)N_TOK;
    const uint32_t nchunks = (count + 31u) >> 5;
    for (uint32_t ch = blockIdx.x; ch < nchunks; ch += gridDim.x) {
        uint32_t slot = ch * 32u + (uint32_t)(lane >> 1);
        bool active = slot < count;
        int tok = 0;
        float na = 0.f, nb = 0.f, op = 0.f;
        if (COMPACT) {
            if (active) {
                uint32_t mt = meta[slot];
                tok = (int)(mt & 0x7FFFu);
                uint32_t nib = mt >> 15;
                na = (float)((nib >> (p * 4)) & 0xFu);
                nb = (float)((nib >> (8 + p * 4)) & 0xFu);
                op = opv[slot];
            }
        } else {
            tok = (int)slot;
            if (active) {
                size_t tb = (size_t)tok * TD;
                float g0 = x[tb], g1 = x[tb + 1];
                active = (g0 >= 0.5f) && (g1 >= 0.5f);
                if (active) {
                    const float* ap = x + tb + 64 + 16 * p;
                    const float* bp = x + tb + 96 + 16 * p;
                    #pragma unroll
                    for (int i = 15; i >= 0; --i) { if (ap[i] > 0.5f) na = (float)i; }
                    #pragma unroll
                    for (int i = 15; i >= 0; --i) { if (bp[i] > 0.5f) nb = (float)i; }
                    op = x[tb + 29];
                }
            }
        }
        float c[10];
        {
            #pragma unroll
            for (int j = 0; j < 10; ++j) {
                int n = 10 * w + j;
                float cc = b[n];
                cc = fmaf(W[n * GE + 0],  na, cc);
                cc = fmaf(W[n * GE + 1],  nb, cc);
                cc = fmaf(W[n * GE + 30], op, cc);
                c[j] = fmaxf(cc, 0.f);
            }
        }
        __syncthreads();
        #pragma unroll
        for (int j = 0; j < 10; ++j) h[10 * w + j][lane] = c[j];
        __syncthreads();
        for (int l = 1; l < 6; ++l) {
            const float* Wl = W + l * WSTRIDE;
            const float* bl = b + l * GE;
            #pragma unroll
            for (int j = 0; j < 10; ++j) c[j] = bl[10 * w + j];
            for (int k0 = 0; k0 < GE; k0 += 16) {
                float hr[16];
                #pragma unroll
                for (int kk = 0; kk < 16; ++kk) hr[kk] = h[k0 + kk][lane];
                #pragma unroll
                for (int j = 0; j < 10; ++j) {
                    const float* wr = Wl + (10 * w + j) * GE + k0;
                    #pragma unroll
                    for (int kk = 0; kk < 16; ++kk)
                        c[j] = fmaf(hr[kk], wr[kk], c[j]);
                }
            }
            __syncthreads();
            #pragma unroll
            for (int j = 0; j < 10; ++j)
                h[10 * w + j][lane] = fmaxf(c[j], 0.f);
            __syncthreads();
        }
        if (w == 0) {
            const float* W6 = W + 6 * WSTRIDE + 2 * GE;
            float acc = b[6 * GE + 2];
            #pragma unroll 16
            for (int k = 0; k < GE; ++k) acc = fmaf(h[k][lane], W6[k], acc);
            if (active) {
                float r = rintf(acc);
                r = fminf(fmaxf(r, 0.f), 15.f);
                int res = (int)r;
                out[(size_t)tok * TD + 128 + 16 * p + res] += 2.0f;
            }
        }
    }
}

extern "C" void kernel_launch(void* const* d_in, const int* in_sizes, int n_in,
                              void* d_out, int out_size, void* d_ws, size_t ws_size,
                              hipStream_t stream) {
    const float* x = (const float*)d_in[0];
    const float* W = (const float*)d_in[1];
    const float* b = (const float*)d_in[2];
    float* out = (float*)d_out;

    if (ws_size >= (size_t)WS_REQ) {
        float4* l0c = (float4*)((char*)d_ws + OFF_L0C);
        unsigned short* Wf = (unsigned short*)((char*)d_ws + OFF_WF);
        wprep_kernel<<<64, 256, 0, stream>>>(W, b, l0c, Wf);
        mega2_kernel<<<N_TOK / 32, 256, 0, stream>>>(x, W, b, out, l0c, Wf);
    } else {
        uint32_t* cnt  = (uint32_t*)((char*)d_ws + LOFF_CNT);
        uint32_t* meta = (uint32_t*)((char*)d_ws + LOFF_META);
        float*    opv  = (float*)((char*)d_ws + LOFF_OPV);
        bool compact = ws_size >= (size_t)(256 + 8 * (size_t)N_TOK);
        if (compact) hipMemsetAsync(d_ws, 0, 4, stream);
        prep_legacy<<<N_TOK / 32, 256, 0, stream>>>(x, out, cnt, meta, opv,
                                                    compact ? 1 : 0);
        if (compact)
            mlp_legacy<true><<<512, 1024, 0, stream>>>(x, W, b, out, cnt, meta, opv);
        else
            mlp_legacy<false><<<512, 1024, 0, stream>>>(x, W, b, out, cnt, meta, opv);
    }
}